// Round 1
// baseline (111.066 us; speedup 1.0000x reference)
//
#include <hip/hip_runtime.h>

// R17: single-variable probe — raise the compiler's VGPR budget.
// Base (R14 best): total 107.9us, kernel 47.4us, VGPR 40, Occ 46.8%, VALU 44%.
// Diagnosis: latency equilibrium. VALU issue ~21us, LDS ~18us, HBM 7% — no
// pipe >45%. VGPR=40 means the compiler serialized the 9 dependent taps
// (addr -> ds_read(~120cy) -> fma) to chase 8-waves/SIMD occupancy that the
// HW doesn't deliver (measured 3.75 waves/SIMD). __launch_bounds__(256,4)
// sets min-waves/EU=4 -> 128-VGPR budget -> pre-RA scheduler batches 3-4
// taps' LDS loads in flight. Occupancy cap 50% == today's measured residency,
// so no real TLP is lost; per-wave ILP should ~2-4x.
// Predicted: VGPR -> 96-128, VALUBusy -> 55-70%, kernel -> 36-42us.
//
// Fused: offset = conv3x3(x,w1)+b1 ; out = deform_conv(x, offset, w2)+b2
// x: (8,3,384,384) f32 NCHW ; out: (8,3,382,382) f32
//
// Verified wins kept: XCD batch swizzle; NHWC4 LDS halo tile staged straight
// from NCHW; pk_fma packing; NT stores; interior fast path + exact fixup.
// Known dead ends: VGPR caps below pressure (R3); >1 px/thread (R2); manual
// source pipelining (R9/R12); branch in unrolled tap loop (R10); 512-thread
// blocks (R15); unified path everywhere (R16).

#define BB 8
#define HH 384
#define WW 384
#define HO 382
#define WO 382
#define HW (HH * WW)
#define TW 32
#define TH 8
#define TILES_X 12               // ceil(382/32)
#define TILES_Y 48               // ceil(382/8)
#define SROWS 15                 // rows r0-2 .. r0+12
#define SCOLS 39                 // cols w0-2 .. w0+36
#define SSTRIDE 39

typedef float v2f __attribute__((ext_vector_type(2), aligned(4)));
typedef float v4f __attribute__((ext_vector_type(4), aligned(16)));

static __device__ __forceinline__ v2f fma2(v2f a, v2f b, v2f c) {
    return __builtin_elementwise_fma(a, b, c);
}
static __device__ __forceinline__ v4f fma4(v4f a, v4f b, v4f c) {
    return __builtin_elementwise_fma(a, b, c);
}

__global__ __launch_bounds__(256, 4) void deform_tiled(
    const float* __restrict__ x,
    const float* __restrict__ w1,
    const float* __restrict__ b1,
    const float* __restrict__ w2,
    const float* __restrict__ b2,
    float* __restrict__ out)
{
    __shared__ v4f  s_tile[SROWS * SSTRIDE];   // 585*16 = 9.4KB
    __shared__ float s_w1p[486];   // pairs: [((j*3+c)*9+k)*2+comp]
    __shared__ float s_b1[18];
    __shared__ float s_w2p[54];    // pairs (o=0,1): [(k*3+c)*2+o]
    __shared__ float s_w2s[27];    // scalar o=2:    [k*3+c]
    __shared__ float s_b2[3];

    for (int i = threadIdx.x; i < 486; i += 256) {
        const int oc = i / 27, rem = i % 27, c = rem / 9, j = rem % 9;
        const int k = oc >> 1, comp = oc & 1;
        s_w1p[((j * 3 + c) * 9 + k) * 2 + comp] = w1[i];
    }
    if (threadIdx.x < 81) {
        const int i = threadIdx.x;
        const int o = i / 27, c = (i % 27) / 9, k = i % 9;
        if (o < 2) s_w2p[(k * 3 + c) * 2 + o] = w2[i];
        else       s_w2s[k * 3 + c] = w2[i];
    }
    if (threadIdx.x < 18) s_b1[threadIdx.x] = b1[threadIdx.x];
    if (threadIdx.x < 3)  s_b2[threadIdx.x] = b2[threadIdx.x];

    const int b  = blockIdx.x & 7;            // XCD-locality: batch per XCD
    const int t  = blockIdx.x >> 3;
    const int tx = t % TILES_X;
    const int ty = t / TILES_X;
    const int w0 = tx * TW;
    const int r0 = ty * TH;

    const float* xp0 = x + (long)b * 3 * HW;
    const float* xp1 = xp0 + HW;
    const float* xp2 = xp0 + 2 * HW;

    // ---- stage halo tile, transposing NCHW -> NHWC4 on the fly ----
    const int gr0 = r0 - 2, gc0 = w0 - 2;
    for (int s = threadIdx.x; s < SROWS * SCOLS; s += 256) {
        const int sr = s / SCOLS, sc = s - sr * SCOLS;
        const int gy = min(max(gr0 + sr, 0), HH - 1);
        const int gx = min(max(gc0 + sc, 0), WW - 1);
        const int base = gy * WW + gx;
        v4f v;
        v.x = xp0[base];
        v.y = xp1[base];
        v.z = xp2[base];
        v.w = 0.f;
        s_tile[sr * SSTRIDE + sc] = v;
    }
    __syncthreads();

    const int wo_in = threadIdx.x & 31;
    const int ho_in = threadIdx.x >> 5;
    const int wo = w0 + wo_in;
    const int ho = r0 + ho_in;
    if (wo >= WO || ho >= HO) return;         // after the only barrier

    // ---- Phase 1: 9 (dy,dx) pairs from LDS tile, packed FMA ----
    v2f off2[9];
#pragma unroll
    for (int k = 0; k < 9; ++k) {
        v2f v; v.x = s_b1[2 * k]; v.y = s_b1[2 * k + 1];
        off2[k] = v;
    }

    const v2f* w1p = (const v2f*)s_w1p;
#pragma unroll
    for (int j = 0; j < 9; ++j) {
        const int i = j / 3, jj = j % 3;
        const v4f q = s_tile[(ho_in + 2 + i) * SSTRIDE + (wo_in + 2 + jj)];
#pragma unroll
        for (int c = 0; c < 3; ++c) {
            const float xc = (c == 0) ? q.x : (c == 1) ? q.y : q.z;
            v2f xcv; xcv.x = xc; xcv.y = xc;
            const v2f* wrow = w1p + (j * 3 + c) * 9;
#pragma unroll
            for (int k = 0; k < 9; ++k)
                off2[k] = fma2(xcv, wrow[k], off2[k]);
        }
    }

    // ---- Phase 2 ----
    float acc0 = s_b2[0], acc1 = s_b2[1], acc2 = s_b2[2];
    const v2f* w2p = (const v2f*)s_w2p;

    const bool interior = (gr0 >= 0) & (gc0 >= 0) &
                          (gr0 + SROWS <= HH) & (gc0 + SCOLS <= WW);

    if (interior) {
        // ======== Pass A: fully unrolled, branchless, mask collection ======
        unsigned bad = 0u;
#pragma unroll
        for (int k = 0; k < 9; ++k) {
            const int kh = k / 3, kw = k - kh * 3;
            v2f pos; pos.x = (float)(ho + kh); pos.y = (float)(wo + kw);
            pos += off2[k];
            const v2f fl = __builtin_elementwise_floor(pos);
            const v2f fr = pos - fl;
            const int y0 = (int)fl.x;
            const int x0 = (int)fl.y;
            const int ly0 = y0 - gr0;
            const int lx  = x0 - gc0;

            bad |= (((unsigned)ly0 > (unsigned)(SROWS - 2)) |
                    ((unsigned)lx  > (unsigned)(SCOLS - 2))) ? (1u << k) : 0u;

            const float g00 = (1.f - fr.x) * (1.f - fr.y);
            const float g01 = (1.f - fr.x) * fr.y;
            const float g10 = fr.x * (1.f - fr.y);
            const float g11 = fr.x * fr.y;

            const int cy0 = min(max(ly0, 0), SROWS - 2);
            const int cx  = min(max(lx, 0),  SCOLS - 2);
            const v4f* p0 = s_tile + cy0 * SSTRIDE + cx;
            const v4f* p1 = p0 + SSTRIDE;
            const v4f q00 = p0[0], q01 = p0[1];
            const v4f q10 = p1[0], q11 = p1[1];

            v4f gv; gv.x = g00; gv.y = g00; gv.z = g00; gv.w = g00;
            v4f t4 = gv * q00;
            gv.x = g01; gv.y = g01; gv.z = g01; gv.w = g01;
            t4 = fma4(gv, q01, t4);
            gv.x = g10; gv.y = g10; gv.z = g10; gv.w = g10;
            t4 = fma4(gv, q10, t4);
            gv.x = g11; gv.y = g11; gv.z = g11; gv.w = g11;
            t4 = fma4(gv, q11, t4);

            const float v0 = t4.x, v1 = t4.y, v2v = t4.z;

            v2f acc01; acc01.x = acc0; acc01.y = acc1;
            v2f vv;
            vv.x = v0;  vv.y = v0;  acc01 = fma2(vv, w2p[k * 3 + 0], acc01);
            vv.x = v1;  vv.y = v1;  acc01 = fma2(vv, w2p[k * 3 + 1], acc01);
            vv.x = v2v; vv.y = v2v; acc01 = fma2(vv, w2p[k * 3 + 2], acc01);
            acc0 = acc01.x; acc1 = acc01.y;
            acc2 = fmaf(s_w2s[k * 3 + 0], v0, acc2);
            acc2 = fmaf(s_w2s[k * 3 + 1], v1, acc2);
            acc2 = fmaf(s_w2s[k * 3 + 2], v2v, acc2);
        }

        // ======== Pass B: exact fixup for >8-sigma taps (execz-skipped) ====
        if (bad) {
#pragma unroll 1
            for (int k = 0; k < 9; ++k) {
                if ((bad >> k) & 1u) {
                    const int kh = k / 3, kw = k - kh * 3;
                    v2f pos; pos.x = (float)(ho + kh); pos.y = (float)(wo + kw);
                    pos += off2[k];
                    const v2f fl = __builtin_elementwise_floor(pos);
                    const v2f fr = pos - fl;
                    const int y0 = (int)fl.x;
                    const int x0 = (int)fl.y;

                    // -- wrong contribution (identical ops to pass A) --
                    const int ly0 = y0 - gr0;
                    const int lx  = x0 - gc0;
                    const float a00 = (1.f - fr.x) * (1.f - fr.y);
                    const float a01 = (1.f - fr.x) * fr.y;
                    const float a10 = fr.x * (1.f - fr.y);
                    const float a11 = fr.x * fr.y;
                    const int cy0 = min(max(ly0, 0), SROWS - 2);
                    const int cx  = min(max(lx, 0),  SCOLS - 2);
                    const v4f* p0 = s_tile + cy0 * SSTRIDE + cx;
                    const v4f* p1 = p0 + SSTRIDE;
                    const v4f w00v = p0[0], w01v = p0[1];
                    const v4f w10v = p1[0], w11v = p1[1];
                    v4f gv; gv.x = a00; gv.y = a00; gv.z = a00; gv.w = a00;
                    v4f tw = gv * w00v;
                    gv.x = a01; gv.y = a01; gv.z = a01; gv.w = a01;
                    tw = fma4(gv, w01v, tw);
                    gv.x = a10; gv.y = a10; gv.z = a10; gv.w = a10;
                    tw = fma4(gv, w10v, tw);
                    gv.x = a11; gv.y = a11; gv.z = a11; gv.w = a11;
                    tw = fma4(gv, w11v, tw);

                    // -- right contribution (exact reference semantics) --
                    const int ry0 = min(max(y0, 0), HH - 1);
                    const int ry1 = min(max(y0 + 1, 0), HH - 1);
                    const int xbs = min(max(x0, 0), WW - 2);
                    const bool vy0 = (y0 >= 0) & (y0 <= HH - 1);
                    const bool vy1 = (y0 >= -1) & (y0 <= HH - 2);
                    const bool vx0 = (x0 >= 0) & (x0 <= WW - 1);
                    const bool vx1 = (x0 >= -1) & (x0 <= WW - 2);
                    const float wy0m = vy0 ? (1.f - fr.x) : 0.f;
                    const float wy1m = vy1 ? fr.x : 0.f;
                    const float wx0m = vx0 ? (1.f - fr.y) : 0.f;
                    const float wx1m = vx1 ? fr.y : 0.f;
                    const bool selA = (x0 >= WW - 1);
                    const bool selB = (x0 >= 0);
                    const float e0 = (selA ? 0.f : wx0m) + (selB ? 0.f : wx1m);
                    const float e1 = (selA ? wx0m : 0.f) + (selB ? wx1m : 0.f);
                    const float g00 = wy0m * e0, g01 = wy0m * e1;
                    const float g10 = wy1m * e0, g11 = wy1m * e1;
                    const int o0 = ry0 * WW + xbs;
                    const int o1 = ry1 * WW + xbs;
                    v4f q00, q01, q10, q11;
                    q00.x = xp0[o0];     q00.y = xp1[o0];     q00.z = xp2[o0];     q00.w = 0.f;
                    q01.x = xp0[o0 + 1]; q01.y = xp1[o0 + 1]; q01.z = xp2[o0 + 1]; q01.w = 0.f;
                    q10.x = xp0[o1];     q10.y = xp1[o1];     q10.z = xp2[o1];     q10.w = 0.f;
                    q11.x = xp0[o1 + 1]; q11.y = xp1[o1 + 1]; q11.z = xp2[o1 + 1]; q11.w = 0.f;
                    gv.x = g00; gv.y = g00; gv.z = g00; gv.w = g00;
                    v4f tr = gv * q00;
                    gv.x = g01; gv.y = g01; gv.z = g01; gv.w = g01;
                    tr = fma4(gv, q01, tr);
                    gv.x = g10; gv.y = g10; gv.z = g10; gv.w = g10;
                    tr = fma4(gv, q10, tr);
                    gv.x = g11; gv.y = g11; gv.z = g11; gv.w = g11;
                    tr = fma4(gv, q11, tr);

                    const float d0 = tr.x - tw.x;
                    const float d1 = tr.y - tw.y;
                    const float d2 = tr.z - tw.z;

                    v2f acc01; acc01.x = acc0; acc01.y = acc1;
                    v2f vv;
                    vv.x = d0; vv.y = d0; acc01 = fma2(vv, w2p[k * 3 + 0], acc01);
                    vv.x = d1; vv.y = d1; acc01 = fma2(vv, w2p[k * 3 + 1], acc01);
                    vv.x = d2; vv.y = d2; acc01 = fma2(vv, w2p[k * 3 + 2], acc01);
                    acc0 = acc01.x; acc1 = acc01.y;
                    acc2 = fmaf(s_w2s[k * 3 + 0], d0, acc2);
                    acc2 = fmaf(s_w2s[k * 3 + 1], d1, acc2);
                    acc2 = fmaf(s_w2s[k * 3 + 2], d2, acc2);
                }
            }
        }
    } else {
        // ---- border blocks (20%): rolled exact loop ----
#pragma unroll 1
        for (int k = 0; k < 9; ++k) {
            const int kh = k / 3, kw = k - kh * 3;
            v2f pos; pos.x = (float)(ho + kh); pos.y = (float)(wo + kw);
            pos += off2[k];
            const v2f fl = __builtin_elementwise_floor(pos);
            const v2f fr = pos - fl;
            const int y0 = (int)fl.x;
            const int x0 = (int)fl.y;

            const int ry0 = min(max(y0, 0), HH - 1);
            const int ry1 = min(max(y0 + 1, 0), HH - 1);
            const int xbs = min(max(x0, 0), WW - 2);

            const bool vy0 = (y0 >= 0) & (y0 <= HH - 1);
            const bool vy1 = (y0 >= -1) & (y0 <= HH - 2);
            const bool vx0 = (x0 >= 0) & (x0 <= WW - 1);
            const bool vx1 = (x0 >= -1) & (x0 <= WW - 2);
            const float wy0m = vy0 ? (1.f - fr.x) : 0.f;
            const float wy1m = vy1 ? fr.x : 0.f;
            const float wx0m = vx0 ? (1.f - fr.y) : 0.f;
            const float wx1m = vx1 ? fr.y : 0.f;

            const bool selA = (x0 >= WW - 1);
            const bool selB = (x0 >= 0);
            const float e0 = (selA ? 0.f : wx0m) + (selB ? 0.f : wx1m);
            const float e1 = (selA ? wx0m : 0.f) + (selB ? wx1m : 0.f);
            const float g00 = wy0m * e0, g01 = wy0m * e1;
            const float g10 = wy1m * e0, g11 = wy1m * e1;

            const int ly0 = ry0 - gr0;
            const int ly1 = ry1 - gr0;
            const int lx  = xbs - gc0;
            const bool inTile = ((unsigned)ly0 <= SROWS - 1) &
                                ((unsigned)ly1 <= SROWS - 1) &
                                ((unsigned)lx  <= SCOLS - 2);

            const int cy0 = min(max(ly0, 0), SROWS - 1);
            const int cy1 = min(max(ly1, 0), SROWS - 1);
            const int cx  = min(max(lx, 0),  SCOLS - 2);
            const v4f* p0 = s_tile + cy0 * SSTRIDE + cx;
            const v4f* p1 = s_tile + cy1 * SSTRIDE + cx;
            v4f q00 = p0[0], q01 = p0[1];
            v4f q10 = p1[0], q11 = p1[1];

            if (!inTile) {
                const int o0 = ry0 * WW + xbs;
                const int o1 = ry1 * WW + xbs;
                q00.x = xp0[o0];     q00.y = xp1[o0];     q00.z = xp2[o0];
                q01.x = xp0[o0 + 1]; q01.y = xp1[o0 + 1]; q01.z = xp2[o0 + 1];
                q10.x = xp0[o1];     q10.y = xp1[o1];     q10.z = xp2[o1];
                q11.x = xp0[o1 + 1]; q11.y = xp1[o1 + 1]; q11.z = xp2[o1 + 1];
            }

            v4f gv; gv.x = g00; gv.y = g00; gv.z = g00; gv.w = g00;
            v4f t4 = gv * q00;
            gv.x = g01; gv.y = g01; gv.z = g01; gv.w = g01;
            t4 = fma4(gv, q01, t4);
            gv.x = g10; gv.y = g10; gv.z = g10; gv.w = g10;
            t4 = fma4(gv, q10, t4);
            gv.x = g11; gv.y = g11; gv.z = g11; gv.w = g11;
            t4 = fma4(gv, q11, t4);

            const float v0 = t4.x, v1 = t4.y, v2v = t4.z;

            v2f acc01; acc01.x = acc0; acc01.y = acc1;
            v2f vv;
            vv.x = v0;  vv.y = v0;  acc01 = fma2(vv, w2p[k * 3 + 0], acc01);
            vv.x = v1;  vv.y = v1;  acc01 = fma2(vv, w2p[k * 3 + 1], acc01);
            vv.x = v2v; vv.y = v2v; acc01 = fma2(vv, w2p[k * 3 + 2], acc01);
            acc0 = acc01.x; acc1 = acc01.y;
            acc2 = fmaf(s_w2s[k * 3 + 0], v0, acc2);
            acc2 = fmaf(s_w2s[k * 3 + 1], v1, acc2);
            acc2 = fmaf(s_w2s[k * 3 + 2], v2v, acc2);
        }
    }

    const long obase = ((long)(b * 3) * HO + ho) * WO + wo;
    __builtin_nontemporal_store(acc0, out + obase);
    __builtin_nontemporal_store(acc1, out + obase + (long)HO * WO);
    __builtin_nontemporal_store(acc2, out + obase + 2L * HO * WO);
}

extern "C" void kernel_launch(void* const* d_in, const int* in_sizes, int n_in,
                              void* d_out, int out_size, void* d_ws, size_t ws_size,
                              hipStream_t stream) {
    const float* x  = (const float*)d_in[0];
    const float* w1 = (const float*)d_in[1];
    const float* b1 = (const float*)d_in[2];
    const float* w2 = (const float*)d_in[3];
    const float* b2 = (const float*)d_in[4];
    float* out = (float*)d_out;

    const int blocks = TILES_X * TILES_Y * BB;   // 12*48*8 = 4608
    deform_tiled<<<blocks, 256, 0, stream>>>(x, w1, b1, w2, b2, out);
}

// Round 2
// 107.431 us; speedup vs baseline: 1.0338x; 1.0338x over previous
//
#include <hip/hip_runtime.h>

// R18: split-plane duplicated-pair LDS layout — cut LDS bytes/tap 25%.
// History: R14 best 47.4us kernel / 107.9 total (VGPR40, Occ47, VALU44).
// R17 (launch_bounds(256,4)): VGPR 40->36, Occ ->54.5%, dur UNCHANGED ->
// falsified "register-budget serialization"; TLP also ruled out (more waves,
// same time). Remaining theory: LDS pipe ~45-50% busy (144 b128/block phase-2
// + 3.1M conflict cycles) coupled to VALU 46% by the dependent chain.
// This round: s_p01[r][c]={c0[c],c1[c],c0[c+1],c1[c+1]} (b128 = both corners
// x 2ch), s_p2[r][c]={c2[c],c2[c+1]} (b64 per row, rows merge to ds_read2).
// Per tap 64B/4insts -> 48B/(2 b128+2 b64). VALU unchanged.
// Predicted: dur 47.3 -> 42-44.5us if LDS-throughput-gated; if unchanged,
// LDS throughput exonerated -> pivot to fp16 tile (halve deps) next.
//
// Fused: offset = conv3x3(x,w1)+b1 ; out = deform_conv(x, offset, w2)+b2
// x: (8,3,384,384) f32 NCHW ; out: (8,3,382,382) f32

#define BB 8
#define HH 384
#define WW 384
#define HO 382
#define WO 382
#define HW (HH * WW)
#define TW 32
#define TH 8
#define TILES_X 12               // ceil(382/32)
#define TILES_Y 48               // ceil(382/8)
#define SROWS 15                 // rows r0-2 .. r0+12
#define SCOLS 39                 // cols w0-2 .. w0+36
#define SSTRIDE 39

typedef float v2f __attribute__((ext_vector_type(2), aligned(8)));
typedef float v4f __attribute__((ext_vector_type(4), aligned(16)));

static __device__ __forceinline__ v2f fma2(v2f a, v2f b, v2f c) {
    return __builtin_elementwise_fma(a, b, c);
}
static __device__ __forceinline__ v2f lo2(v4f v) { v2f r; r.x = v.x; r.y = v.y; return r; }
static __device__ __forceinline__ v2f hi2(v4f v) { v2f r; r.x = v.z; r.y = v.w; return r; }
static __device__ __forceinline__ v2f bc2(float f) { v2f r; r.x = f; r.y = f; return r; }

__global__ __launch_bounds__(256, 4) void deform_tiled(
    const float* __restrict__ x,
    const float* __restrict__ w1,
    const float* __restrict__ b1,
    const float* __restrict__ w2,
    const float* __restrict__ b2,
    float* __restrict__ out)
{
    __shared__ v4f  s_p01[SROWS * SSTRIDE];  // {c0[c],c1[c],c0[c+1],c1[c+1]} 9360B
    __shared__ v2f  s_p2 [SROWS * SSTRIDE];  // {c2[c],c2[c+1]}               4680B
    __shared__ float s_w1p[486];   // pairs: [((j*3+c)*9+k)*2+comp]
    __shared__ float s_b1[18];
    __shared__ float s_w2p[54];    // pairs (o=0,1): [(k*3+c)*2+o]
    __shared__ float s_w2s[27];    // scalar o=2:    [k*3+c]
    __shared__ float s_b2[3];

    for (int i = threadIdx.x; i < 486; i += 256) {
        const int oc = i / 27, rem = i % 27, c = rem / 9, j = rem % 9;
        const int k = oc >> 1, comp = oc & 1;
        s_w1p[((j * 3 + c) * 9 + k) * 2 + comp] = w1[i];
    }
    if (threadIdx.x < 81) {
        const int i = threadIdx.x;
        const int o = i / 27, c = (i % 27) / 9, k = i % 9;
        if (o < 2) s_w2p[(k * 3 + c) * 2 + o] = w2[i];
        else       s_w2s[k * 3 + c] = w2[i];
    }
    if (threadIdx.x < 18) s_b1[threadIdx.x] = b1[threadIdx.x];
    if (threadIdx.x < 3)  s_b2[threadIdx.x] = b2[threadIdx.x];

    const int b  = blockIdx.x & 7;            // XCD-locality: batch per XCD
    const int t  = blockIdx.x >> 3;
    const int tx = t % TILES_X;
    const int ty = t / TILES_X;
    const int w0 = tx * TW;
    const int r0 = ty * TH;

    const float* xp0 = x + (long)b * 3 * HW;
    const float* xp1 = xp0 + HW;
    const float* xp2 = xp0 + 2 * HW;

    // ---- stage halo tile: 3 global loads/entry, scatter halves into the
    //      duplicated-pair planes (own .xy/.x, left neighbor's .zw/.y) ----
    const int gr0 = r0 - 2, gc0 = w0 - 2;
    for (int s = threadIdx.x; s < SROWS * SCOLS; s += 256) {
        const int sr = s / SCOLS, sc = s - sr * SCOLS;
        const int gy = min(max(gr0 + sr, 0), HH - 1);
        const int gx = min(max(gc0 + sc, 0), WW - 1);
        const int base = gy * WW + gx;
        const float c0 = xp0[base];
        const float c1 = xp1[base];
        const float c2 = xp2[base];
        v2f p; p.x = c0; p.y = c1;
        const int e = sr * SSTRIDE + sc;
        *(v2f*)(&s_p01[e]) = p;                     // entry e, cols {c}
        s_p2[e].x = c2;
        if (sc > 0) {
            *((v2f*)(&s_p01[e - 1]) + 1) = p;       // entry e-1, col {c} as c+1
            s_p2[e - 1].y = c2;
        }
    }
    __syncthreads();

    const int wo_in = threadIdx.x & 31;
    const int ho_in = threadIdx.x >> 5;
    const int wo = w0 + wo_in;
    const int ho = r0 + ho_in;
    if (wo >= WO || ho >= HO) return;         // after the only barrier

    // ---- Phase 1: 9 (dy,dx) pairs from LDS tile, packed FMA ----
    v2f off2[9];
#pragma unroll
    for (int k = 0; k < 9; ++k) {
        v2f v; v.x = s_b1[2 * k]; v.y = s_b1[2 * k + 1];
        off2[k] = v;
    }

    const v2f* w1p = (const v2f*)s_w1p;
    const int pc = wo_in + 2;
#pragma unroll
    for (int i = 0; i < 3; ++i) {
        const int rowb = (ho_in + 2 + i) * SSTRIDE + pc;
        const v4f pa = s_p01[rowb];       // c01 @ jj=0,1
        const v4f pb = s_p01[rowb + 2];   // c01 @ jj=2 (+waste)
        const v2f sa = s_p2[rowb];        // c2  @ jj=0,1
        const v2f sb = s_p2[rowb + 2];    // c2  @ jj=2 (+waste)
        const float xs0[3] = { pa.x, pa.y, sa.x };
        const float xs1[3] = { pa.z, pa.w, sa.y };
        const float xs2[3] = { pb.x, pb.y, sb.x };
#pragma unroll
        for (int jj = 0; jj < 3; ++jj) {
            const int j = i * 3 + jj;
#pragma unroll
            for (int c = 0; c < 3; ++c) {
                const float xc = (jj == 0) ? xs0[c] : (jj == 1) ? xs1[c] : xs2[c];
                const v2f xcv = bc2(xc);
                const v2f* wrow = w1p + (j * 3 + c) * 9;
#pragma unroll
                for (int k = 0; k < 9; ++k)
                    off2[k] = fma2(xcv, wrow[k], off2[k]);
            }
        }
    }

    // ---- Phase 2 ----
    float acc0 = s_b2[0], acc1 = s_b2[1], acc2 = s_b2[2];
    const v2f* w2p = (const v2f*)s_w2p;

    const bool interior = (gr0 >= 0) & (gc0 >= 0) &
                          (gr0 + SROWS <= HH) & (gc0 + SCOLS <= WW);

    if (interior) {
        // ======== Pass A: fully unrolled, branchless, mask collection ======
        unsigned bad = 0u;
#pragma unroll
        for (int k = 0; k < 9; ++k) {
            const int kh = k / 3, kw = k - kh * 3;
            v2f pos; pos.x = (float)(ho + kh); pos.y = (float)(wo + kw);
            pos += off2[k];
            const v2f fl = __builtin_elementwise_floor(pos);
            const v2f fr = pos - fl;
            const int y0 = (int)fl.x;
            const int x0 = (int)fl.y;
            const int ly0 = y0 - gr0;
            const int lx  = x0 - gc0;

            bad |= (((unsigned)ly0 > (unsigned)(SROWS - 2)) |
                    ((unsigned)lx  > (unsigned)(SCOLS - 2))) ? (1u << k) : 0u;

            const float g00 = (1.f - fr.x) * (1.f - fr.y);
            const float g01 = (1.f - fr.x) * fr.y;
            const float g10 = fr.x * (1.f - fr.y);
            const float g11 = fr.x * fr.y;

            const int cy0 = min(max(ly0, 0), SROWS - 2);
            const int cx  = min(max(lx, 0),  SCOLS - 2);
            const int ib  = cy0 * SSTRIDE + cx;
            const v4f r0v = s_p01[ib];
            const v4f r1v = s_p01[ib + SSTRIDE];
            const v2f s0v = s_p2[ib];
            const v2f s1v = s_p2[ib + SSTRIDE];

            v2f t01 = bc2(g00) * lo2(r0v);
            t01 = fma2(bc2(g01), hi2(r0v), t01);
            t01 = fma2(bc2(g10), lo2(r1v), t01);
            t01 = fma2(bc2(g11), hi2(r1v), t01);
            float t2 = g00 * s0v.x;
            t2 = fmaf(g01, s0v.y, t2);
            t2 = fmaf(g10, s1v.x, t2);
            t2 = fmaf(g11, s1v.y, t2);

            const float v0 = t01.x, v1 = t01.y, v2v = t2;

            v2f acc01; acc01.x = acc0; acc01.y = acc1;
            acc01 = fma2(bc2(v0),  w2p[k * 3 + 0], acc01);
            acc01 = fma2(bc2(v1),  w2p[k * 3 + 1], acc01);
            acc01 = fma2(bc2(v2v), w2p[k * 3 + 2], acc01);
            acc0 = acc01.x; acc1 = acc01.y;
            acc2 = fmaf(s_w2s[k * 3 + 0], v0, acc2);
            acc2 = fmaf(s_w2s[k * 3 + 1], v1, acc2);
            acc2 = fmaf(s_w2s[k * 3 + 2], v2v, acc2);
        }

        // ======== Pass B: exact fixup for >8-sigma taps (execz-skipped) ====
        if (bad) {
#pragma unroll 1
            for (int k = 0; k < 9; ++k) {
                if ((bad >> k) & 1u) {
                    const int kh = k / 3, kw = k - kh * 3;
                    v2f pos; pos.x = (float)(ho + kh); pos.y = (float)(wo + kw);
                    pos += off2[k];
                    const v2f fl = __builtin_elementwise_floor(pos);
                    const v2f fr = pos - fl;
                    const int y0 = (int)fl.x;
                    const int x0 = (int)fl.y;

                    // -- wrong contribution (bit-identical ops to pass A) --
                    const int ly0 = y0 - gr0;
                    const int lx  = x0 - gc0;
                    const float a00 = (1.f - fr.x) * (1.f - fr.y);
                    const float a01 = (1.f - fr.x) * fr.y;
                    const float a10 = fr.x * (1.f - fr.y);
                    const float a11 = fr.x * fr.y;
                    const int cy0 = min(max(ly0, 0), SROWS - 2);
                    const int cx  = min(max(lx, 0),  SCOLS - 2);
                    const int ib  = cy0 * SSTRIDE + cx;
                    const v4f r0v = s_p01[ib];
                    const v4f r1v = s_p01[ib + SSTRIDE];
                    const v2f s0v = s_p2[ib];
                    const v2f s1v = s_p2[ib + SSTRIDE];
                    v2f tw01 = bc2(a00) * lo2(r0v);
                    tw01 = fma2(bc2(a01), hi2(r0v), tw01);
                    tw01 = fma2(bc2(a10), lo2(r1v), tw01);
                    tw01 = fma2(bc2(a11), hi2(r1v), tw01);
                    float tw2 = a00 * s0v.x;
                    tw2 = fmaf(a01, s0v.y, tw2);
                    tw2 = fmaf(a10, s1v.x, tw2);
                    tw2 = fmaf(a11, s1v.y, tw2);

                    // -- right contribution (exact reference semantics) --
                    const int ry0 = min(max(y0, 0), HH - 1);
                    const int ry1 = min(max(y0 + 1, 0), HH - 1);
                    const int xbs = min(max(x0, 0), WW - 2);
                    const bool vy0 = (y0 >= 0) & (y0 <= HH - 1);
                    const bool vy1 = (y0 >= -1) & (y0 <= HH - 2);
                    const bool vx0 = (x0 >= 0) & (x0 <= WW - 1);
                    const bool vx1 = (x0 >= -1) & (x0 <= WW - 2);
                    const float wy0m = vy0 ? (1.f - fr.x) : 0.f;
                    const float wy1m = vy1 ? fr.x : 0.f;
                    const float wx0m = vx0 ? (1.f - fr.y) : 0.f;
                    const float wx1m = vx1 ? fr.y : 0.f;
                    const bool selA = (x0 >= WW - 1);
                    const bool selB = (x0 >= 0);
                    const float e0 = (selA ? 0.f : wx0m) + (selB ? 0.f : wx1m);
                    const float e1 = (selA ? wx0m : 0.f) + (selB ? wx1m : 0.f);
                    const float g00 = wy0m * e0, g01 = wy0m * e1;
                    const float g10 = wy1m * e0, g11 = wy1m * e1;
                    const int o0 = ry0 * WW + xbs;
                    const int o1 = ry1 * WW + xbs;
                    v4f r0g, r1g; v2f s0g, s1g;
                    r0g.x = xp0[o0];     r0g.y = xp1[o0];
                    r0g.z = xp0[o0 + 1]; r0g.w = xp1[o0 + 1];
                    s0g.x = xp2[o0];     s0g.y = xp2[o0 + 1];
                    r1g.x = xp0[o1];     r1g.y = xp1[o1];
                    r1g.z = xp0[o1 + 1]; r1g.w = xp1[o1 + 1];
                    s1g.x = xp2[o1];     s1g.y = xp2[o1 + 1];
                    v2f tr01 = bc2(g00) * lo2(r0g);
                    tr01 = fma2(bc2(g01), hi2(r0g), tr01);
                    tr01 = fma2(bc2(g10), lo2(r1g), tr01);
                    tr01 = fma2(bc2(g11), hi2(r1g), tr01);
                    float tr2 = g00 * s0g.x;
                    tr2 = fmaf(g01, s0g.y, tr2);
                    tr2 = fmaf(g10, s1g.x, tr2);
                    tr2 = fmaf(g11, s1g.y, tr2);

                    const float d0 = tr01.x - tw01.x;
                    const float d1 = tr01.y - tw01.y;
                    const float d2 = tr2 - tw2;

                    v2f acc01; acc01.x = acc0; acc01.y = acc1;
                    acc01 = fma2(bc2(d0), w2p[k * 3 + 0], acc01);
                    acc01 = fma2(bc2(d1), w2p[k * 3 + 1], acc01);
                    acc01 = fma2(bc2(d2), w2p[k * 3 + 2], acc01);
                    acc0 = acc01.x; acc1 = acc01.y;
                    acc2 = fmaf(s_w2s[k * 3 + 0], d0, acc2);
                    acc2 = fmaf(s_w2s[k * 3 + 1], d1, acc2);
                    acc2 = fmaf(s_w2s[k * 3 + 2], d2, acc2);
                }
            }
        }
    } else {
        // ---- border blocks (20%): rolled exact loop ----
#pragma unroll 1
        for (int k = 0; k < 9; ++k) {
            const int kh = k / 3, kw = k - kh * 3;
            v2f pos; pos.x = (float)(ho + kh); pos.y = (float)(wo + kw);
            pos += off2[k];
            const v2f fl = __builtin_elementwise_floor(pos);
            const v2f fr = pos - fl;
            const int y0 = (int)fl.x;
            const int x0 = (int)fl.y;

            const int ry0 = min(max(y0, 0), HH - 1);
            const int ry1 = min(max(y0 + 1, 0), HH - 1);
            const int xbs = min(max(x0, 0), WW - 2);

            const bool vy0 = (y0 >= 0) & (y0 <= HH - 1);
            const bool vy1 = (y0 >= -1) & (y0 <= HH - 2);
            const bool vx0 = (x0 >= 0) & (x0 <= WW - 1);
            const bool vx1 = (x0 >= -1) & (x0 <= WW - 2);
            const float wy0m = vy0 ? (1.f - fr.x) : 0.f;
            const float wy1m = vy1 ? fr.x : 0.f;
            const float wx0m = vx0 ? (1.f - fr.y) : 0.f;
            const float wx1m = vx1 ? fr.y : 0.f;

            const bool selA = (x0 >= WW - 1);
            const bool selB = (x0 >= 0);
            const float e0 = (selA ? 0.f : wx0m) + (selB ? 0.f : wx1m);
            const float e1 = (selA ? wx0m : 0.f) + (selB ? wx1m : 0.f);
            const float g00 = wy0m * e0, g01 = wy0m * e1;
            const float g10 = wy1m * e0, g11 = wy1m * e1;

            const int ly0 = ry0 - gr0;
            const int ly1 = ry1 - gr0;
            const int lx  = xbs - gc0;
            const bool inTile = ((unsigned)ly0 <= SROWS - 1) &
                                ((unsigned)ly1 <= SROWS - 1) &
                                ((unsigned)lx  <= SCOLS - 2);

            const int cy0 = min(max(ly0, 0), SROWS - 1);
            const int cy1 = min(max(ly1, 0), SROWS - 1);
            const int cx  = min(max(lx, 0),  SCOLS - 2);
            const int ib0 = cy0 * SSTRIDE + cx;
            const int ib1 = cy1 * SSTRIDE + cx;
            v4f r0v = s_p01[ib0];
            v4f r1v = s_p01[ib1];
            v2f s0v = s_p2[ib0];
            v2f s1v = s_p2[ib1];

            if (!inTile) {
                const int o0 = ry0 * WW + xbs;
                const int o1 = ry1 * WW + xbs;
                r0v.x = xp0[o0];     r0v.y = xp1[o0];
                r0v.z = xp0[o0 + 1]; r0v.w = xp1[o0 + 1];
                s0v.x = xp2[o0];     s0v.y = xp2[o0 + 1];
                r1v.x = xp0[o1];     r1v.y = xp1[o1];
                r1v.z = xp0[o1 + 1]; r1v.w = xp1[o1 + 1];
                s1v.x = xp2[o1];     s1v.y = xp2[o1 + 1];
            }

            v2f t01 = bc2(g00) * lo2(r0v);
            t01 = fma2(bc2(g01), hi2(r0v), t01);
            t01 = fma2(bc2(g10), lo2(r1v), t01);
            t01 = fma2(bc2(g11), hi2(r1v), t01);
            float t2 = g00 * s0v.x;
            t2 = fmaf(g01, s0v.y, t2);
            t2 = fmaf(g10, s1v.x, t2);
            t2 = fmaf(g11, s1v.y, t2);

            const float v0 = t01.x, v1 = t01.y, v2v = t2;

            v2f acc01; acc01.x = acc0; acc01.y = acc1;
            acc01 = fma2(bc2(v0),  w2p[k * 3 + 0], acc01);
            acc01 = fma2(bc2(v1),  w2p[k * 3 + 1], acc01);
            acc01 = fma2(bc2(v2v), w2p[k * 3 + 2], acc01);
            acc0 = acc01.x; acc1 = acc01.y;
            acc2 = fmaf(s_w2s[k * 3 + 0], v0, acc2);
            acc2 = fmaf(s_w2s[k * 3 + 1], v1, acc2);
            acc2 = fmaf(s_w2s[k * 3 + 2], v2v, acc2);
        }
    }

    const long obase = ((long)(b * 3) * HO + ho) * WO + wo;
    __builtin_nontemporal_store(acc0, out + obase);
    __builtin_nontemporal_store(acc1, out + obase + (long)HO * WO);
    __builtin_nontemporal_store(acc2, out + obase + 2L * HO * WO);
}

extern "C" void kernel_launch(void* const* d_in, const int* in_sizes, int n_in,
                              void* d_out, int out_size, void* d_ws, size_t ws_size,
                              hipStream_t stream) {
    const float* x  = (const float*)d_in[0];
    const float* w1 = (const float*)d_in[1];
    const float* b1 = (const float*)d_in[2];
    const float* w2 = (const float*)d_in[3];
    const float* b2 = (const float*)d_in[4];
    float* out = (float*)d_out;

    const int blocks = TILES_X * TILES_Y * BB;   // 12*48*8 = 4608
    deform_tiled<<<blocks, 256, 0, stream>>>(x, w1, b1, w2, b2, out);
}

// Round 4
// 104.478 us; speedup vs baseline: 1.0631x; 1.0283x over previous
//
#include <hip/hip_runtime.h>

// R20 = R19 with the d_ws null/size hazard removed (suspected cause of the
// round-3 container failure: prep_weights wrote to d_ws unguarded).
// Theory under test (from R18 post-mortem): phase-1 re-reads all 486 w1
// floats from LDS PER PIXEL (~135 ds_read/thread) + ~30 for w2 = ~3/4 of the
// LDS-pipe load; tile reads are the minority (R18's -25% tile bytes -> only
// -3.5% time). Weights are wave-uniform w/ compile-time indices -> belong on
// the scalar pipe: 1-block prep kernel repacks w1/w2 pair-interleaves into
// d_ws; main kernel reads them via uniform global indices -> s_load -> SGPR
// operands feeding pk-FMA. b1/b2 read uniform from their own args (s_load).
// Fallback (ws unusable): identical kernel with LDS weight repack (= R18).
// Predicted (WS path): VALUBusy 50->62-75%, kernel 45.7->33-39us.
// Falsifier: WS path runs, dur ~46, VALU ~50 -> LDS-weight theory dead ->
// equilibrium is waitcnt/latency-structural -> pivot fp16 tile / MFMA.
//
// Fused: offset = conv3x3(x,w1)+b1 ; out = deform_conv(x, offset, w2)+b2
// x: (8,3,384,384) f32 NCHW ; out: (8,3,382,382) f32

#define BB 8
#define HH 384
#define WW 384
#define HO 382
#define WO 382
#define HW (HH * WW)
#define TW 32
#define TH 8
#define TILES_X 12               // ceil(382/32)
#define TILES_Y 48               // ceil(382/8)
#define SROWS 15                 // rows r0-2 .. r0+12
#define SCOLS 39                 // cols w0-2 .. w0+36
#define SSTRIDE 39

// d_ws float offsets (only used when ws_size permits)
#define WS_W1P 0     // 486 floats: pairs [((j*3+c)*9+k)*2+comp]
#define WS_W2P 512   // 54  floats: pairs (o=0,1) [(k*3+c)*2+o]
#define WS_W2S 576   // 27  floats: scalar o=2   [k*3+c]
#define WS_FLOATS 640

typedef float v2f __attribute__((ext_vector_type(2), aligned(8)));
typedef float v4f __attribute__((ext_vector_type(4), aligned(16)));

static __device__ __forceinline__ v2f fma2(v2f a, v2f b, v2f c) {
    return __builtin_elementwise_fma(a, b, c);
}
static __device__ __forceinline__ v2f lo2(v4f v) { v2f r; r.x = v.x; r.y = v.y; return r; }
static __device__ __forceinline__ v2f hi2(v4f v) { v2f r; r.x = v.z; r.y = v.w; return r; }
static __device__ __forceinline__ v2f bc2(float f) { v2f r; r.x = f; r.y = f; return r; }

__global__ __launch_bounds__(512) void prep_weights(
    const float* __restrict__ w1,
    const float* __restrict__ w2,
    float* __restrict__ ws)
{
    const int i = threadIdx.x;
    if (i < 486) {
        const int oc = i / 27, rem = i % 27, c = rem / 9, j = rem % 9;
        const int k = oc >> 1, comp = oc & 1;
        ws[WS_W1P + ((j * 3 + c) * 9 + k) * 2 + comp] = w1[i];
    }
    if (i < 81) {
        const int o = i / 27, c = (i % 27) / 9, k = i % 9;
        if (o < 2) ws[WS_W2P + (k * 3 + c) * 2 + o] = w2[i];
        else       ws[WS_W2S + k * 3 + c] = w2[i];
    }
}

template<bool USE_WS>
__global__ __launch_bounds__(256, 4) void deform_tiled(
    const float* __restrict__ x,
    const float* __restrict__ w1,
    const float* __restrict__ b1,
    const float* __restrict__ w2,
    const float* __restrict__ b2,
    const float* __restrict__ wsp,
    float* __restrict__ out)
{
    __shared__ v4f  s_p01[SROWS * SSTRIDE];  // {c0[c],c1[c],c0[c+1],c1[c+1]} 9360B
    __shared__ v2f  s_p2 [SROWS * SSTRIDE];  // {c2[c],c2[c+1]}               4680B
    __shared__ float s_w1p[486];             // fallback only
    __shared__ float s_w2p[54];
    __shared__ float s_w2s[27];

    if constexpr (!USE_WS) {
        for (int i = threadIdx.x; i < 486; i += 256) {
            const int oc = i / 27, rem = i % 27, c = rem / 9, j = rem % 9;
            const int k = oc >> 1, comp = oc & 1;
            s_w1p[((j * 3 + c) * 9 + k) * 2 + comp] = w1[i];
        }
        if (threadIdx.x < 81) {
            const int i = threadIdx.x;
            const int o = i / 27, c = (i % 27) / 9, k = i % 9;
            if (o < 2) s_w2p[(k * 3 + c) * 2 + o] = w2[i];
            else       s_w2s[k * 3 + c] = w2[i];
        }
    }

    const v2f*   __restrict__ w1p;
    const v2f*   __restrict__ w2p;
    const float* __restrict__ w2s;
    if constexpr (USE_WS) {
        w1p = (const v2f*)(wsp + WS_W1P);
        w2p = (const v2f*)(wsp + WS_W2P);
        w2s = wsp + WS_W2S;
    } else {
        w1p = (const v2f*)s_w1p;
        w2p = (const v2f*)s_w2p;
        w2s = s_w2s;
    }

    const int b  = blockIdx.x & 7;            // XCD-locality: batch per XCD
    const int t  = blockIdx.x >> 3;
    const int tx = t % TILES_X;
    const int ty = t / TILES_X;
    const int w0 = tx * TW;
    const int r0 = ty * TH;

    const float* xp0 = x + (long)b * 3 * HW;
    const float* xp1 = xp0 + HW;
    const float* xp2 = xp0 + 2 * HW;

    // ---- stage halo tile: 3 global loads/entry, scatter halves into the
    //      duplicated-pair planes (own .xy/.x, left neighbor's .zw/.y) ----
    const int gr0 = r0 - 2, gc0 = w0 - 2;
    for (int s = threadIdx.x; s < SROWS * SCOLS; s += 256) {
        const int sr = s / SCOLS, sc = s - sr * SCOLS;
        const int gy = min(max(gr0 + sr, 0), HH - 1);
        const int gx = min(max(gc0 + sc, 0), WW - 1);
        const int base = gy * WW + gx;
        const float c0 = xp0[base];
        const float c1 = xp1[base];
        const float c2 = xp2[base];
        v2f p; p.x = c0; p.y = c1;
        const int e = sr * SSTRIDE + sc;
        *(v2f*)(&s_p01[e]) = p;                     // entry e, cols {c}
        s_p2[e].x = c2;
        if (sc > 0) {
            *((v2f*)(&s_p01[e - 1]) + 1) = p;       // entry e-1, col {c} as c+1
            s_p2[e - 1].y = c2;
        }
    }
    __syncthreads();

    const int wo_in = threadIdx.x & 31;
    const int ho_in = threadIdx.x >> 5;
    const int wo = w0 + wo_in;
    const int ho = r0 + ho_in;
    if (wo >= WO || ho >= HO) return;         // after the only barrier

    // ---- Phase 1: 9 (dy,dx) pairs; x from LDS tile, w1 pairs uniform ----
    v2f off2[9];
    const v2f* __restrict__ b1p = (const v2f*)b1;   // uniform idx -> s_load
#pragma unroll
    for (int k = 0; k < 9; ++k) off2[k] = b1p[k];

    const int pc = wo_in + 2;
#pragma unroll
    for (int i = 0; i < 3; ++i) {
        const int rowb = (ho_in + 2 + i) * SSTRIDE + pc;
        const v4f pa = s_p01[rowb];       // c01 @ jj=0,1
        const v4f pb = s_p01[rowb + 2];   // c01 @ jj=2 (+waste)
        const v2f sa = s_p2[rowb];        // c2  @ jj=0,1
        const v2f sb = s_p2[rowb + 2];    // c2  @ jj=2 (+waste)
        const float xs0[3] = { pa.x, pa.y, sa.x };
        const float xs1[3] = { pa.z, pa.w, sa.y };
        const float xs2[3] = { pb.x, pb.y, sb.x };
#pragma unroll
        for (int jj = 0; jj < 3; ++jj) {
            const int j = i * 3 + jj;
#pragma unroll
            for (int c = 0; c < 3; ++c) {
                const float xc = (jj == 0) ? xs0[c] : (jj == 1) ? xs1[c] : xs2[c];
                const v2f xcv = bc2(xc);
                const v2f* wrow = w1p + (j * 3 + c) * 9;
#pragma unroll
                for (int k = 0; k < 9; ++k)
                    off2[k] = fma2(xcv, wrow[k], off2[k]);
            }
        }
    }

    // ---- Phase 2 ----
    float acc0 = b2[0], acc1 = b2[1], acc2 = b2[2];  // uniform -> s_load

    const bool interior = (gr0 >= 0) & (gc0 >= 0) &
                          (gr0 + SROWS <= HH) & (gc0 + SCOLS <= WW);

    if (interior) {
        // ======== Pass A: fully unrolled, branchless, mask collection ======
        unsigned bad = 0u;
#pragma unroll
        for (int k = 0; k < 9; ++k) {
            const int kh = k / 3, kw = k - kh * 3;
            v2f pos; pos.x = (float)(ho + kh); pos.y = (float)(wo + kw);
            pos += off2[k];
            const v2f fl = __builtin_elementwise_floor(pos);
            const v2f fr = pos - fl;
            const int y0 = (int)fl.x;
            const int x0 = (int)fl.y;
            const int ly0 = y0 - gr0;
            const int lx  = x0 - gc0;

            bad |= (((unsigned)ly0 > (unsigned)(SROWS - 2)) |
                    ((unsigned)lx  > (unsigned)(SCOLS - 2))) ? (1u << k) : 0u;

            const float g00 = (1.f - fr.x) * (1.f - fr.y);
            const float g01 = (1.f - fr.x) * fr.y;
            const float g10 = fr.x * (1.f - fr.y);
            const float g11 = fr.x * fr.y;

            const int cy0 = min(max(ly0, 0), SROWS - 2);
            const int cx  = min(max(lx, 0),  SCOLS - 2);
            const int ib  = cy0 * SSTRIDE + cx;
            const v4f r0v = s_p01[ib];
            const v4f r1v = s_p01[ib + SSTRIDE];
            const v2f s0v = s_p2[ib];
            const v2f s1v = s_p2[ib + SSTRIDE];

            v2f t01 = bc2(g00) * lo2(r0v);
            t01 = fma2(bc2(g01), hi2(r0v), t01);
            t01 = fma2(bc2(g10), lo2(r1v), t01);
            t01 = fma2(bc2(g11), hi2(r1v), t01);
            float t2 = g00 * s0v.x;
            t2 = fmaf(g01, s0v.y, t2);
            t2 = fmaf(g10, s1v.x, t2);
            t2 = fmaf(g11, s1v.y, t2);

            const float v0 = t01.x, v1 = t01.y, v2v = t2;

            v2f acc01; acc01.x = acc0; acc01.y = acc1;
            acc01 = fma2(bc2(v0),  w2p[k * 3 + 0], acc01);
            acc01 = fma2(bc2(v1),  w2p[k * 3 + 1], acc01);
            acc01 = fma2(bc2(v2v), w2p[k * 3 + 2], acc01);
            acc0 = acc01.x; acc1 = acc01.y;
            acc2 = fmaf(w2s[k * 3 + 0], v0, acc2);
            acc2 = fmaf(w2s[k * 3 + 1], v1, acc2);
            acc2 = fmaf(w2s[k * 3 + 2], v2v, acc2);
        }

        // ======== Pass B: exact fixup for >8-sigma taps (execz-skipped) ====
        if (bad) {
#pragma unroll 1
            for (int k = 0; k < 9; ++k) {
                if ((bad >> k) & 1u) {
                    const int kh = k / 3, kw = k - kh * 3;
                    v2f pos; pos.x = (float)(ho + kh); pos.y = (float)(wo + kw);
                    pos += off2[k];
                    const v2f fl = __builtin_elementwise_floor(pos);
                    const v2f fr = pos - fl;
                    const int y0 = (int)fl.x;
                    const int x0 = (int)fl.y;

                    // -- wrong contribution (bit-identical ops to pass A) --
                    const int ly0 = y0 - gr0;
                    const int lx  = x0 - gc0;
                    const float a00 = (1.f - fr.x) * (1.f - fr.y);
                    const float a01 = (1.f - fr.x) * fr.y;
                    const float a10 = fr.x * (1.f - fr.y);
                    const float a11 = fr.x * fr.y;
                    const int cy0 = min(max(ly0, 0), SROWS - 2);
                    const int cx  = min(max(lx, 0),  SCOLS - 2);
                    const int ib  = cy0 * SSTRIDE + cx;
                    const v4f r0v = s_p01[ib];
                    const v4f r1v = s_p01[ib + SSTRIDE];
                    const v2f s0v = s_p2[ib];
                    const v2f s1v = s_p2[ib + SSTRIDE];
                    v2f tw01 = bc2(a00) * lo2(r0v);
                    tw01 = fma2(bc2(a01), hi2(r0v), tw01);
                    tw01 = fma2(bc2(a10), lo2(r1v), tw01);
                    tw01 = fma2(bc2(a11), hi2(r1v), tw01);
                    float tw2 = a00 * s0v.x;
                    tw2 = fmaf(a01, s0v.y, tw2);
                    tw2 = fmaf(a10, s1v.x, tw2);
                    tw2 = fmaf(a11, s1v.y, tw2);

                    // -- right contribution (exact reference semantics) --
                    const int ry0 = min(max(y0, 0), HH - 1);
                    const int ry1 = min(max(y0 + 1, 0), HH - 1);
                    const int xbs = min(max(x0, 0), WW - 2);
                    const bool vy0 = (y0 >= 0) & (y0 <= HH - 1);
                    const bool vy1 = (y0 >= -1) & (y0 <= HH - 2);
                    const bool vx0 = (x0 >= 0) & (x0 <= WW - 1);
                    const bool vx1 = (x0 >= -1) & (x0 <= WW - 2);
                    const float wy0m = vy0 ? (1.f - fr.x) : 0.f;
                    const float wy1m = vy1 ? fr.x : 0.f;
                    const float wx0m = vx0 ? (1.f - fr.y) : 0.f;
                    const float wx1m = vx1 ? fr.y : 0.f;
                    const bool selA = (x0 >= WW - 1);
                    const bool selB = (x0 >= 0);
                    const float e0 = (selA ? 0.f : wx0m) + (selB ? 0.f : wx1m);
                    const float e1 = (selA ? wx0m : 0.f) + (selB ? wx1m : 0.f);
                    const float g00 = wy0m * e0, g01 = wy0m * e1;
                    const float g10 = wy1m * e0, g11 = wy1m * e1;
                    const int o0 = ry0 * WW + xbs;
                    const int o1 = ry1 * WW + xbs;
                    v4f r0g, r1g; v2f s0g, s1g;
                    r0g.x = xp0[o0];     r0g.y = xp1[o0];
                    r0g.z = xp0[o0 + 1]; r0g.w = xp1[o0 + 1];
                    s0g.x = xp2[o0];     s0g.y = xp2[o0 + 1];
                    r1g.x = xp0[o1];     r1g.y = xp1[o1];
                    r1g.z = xp0[o1 + 1]; r1g.w = xp1[o1 + 1];
                    s1g.x = xp2[o1];     s1g.y = xp2[o1 + 1];
                    v2f tr01 = bc2(g00) * lo2(r0g);
                    tr01 = fma2(bc2(g01), hi2(r0g), tr01);
                    tr01 = fma2(bc2(g10), lo2(r1g), tr01);
                    tr01 = fma2(bc2(g11), hi2(r1g), tr01);
                    float tr2 = g00 * s0g.x;
                    tr2 = fmaf(g01, s0g.y, tr2);
                    tr2 = fmaf(g10, s1g.x, tr2);
                    tr2 = fmaf(g11, s1g.y, tr2);

                    const float d0 = tr01.x - tw01.x;
                    const float d1 = tr01.y - tw01.y;
                    const float d2 = tr2 - tw2;

                    v2f acc01; acc01.x = acc0; acc01.y = acc1;
                    acc01 = fma2(bc2(d0), w2p[k * 3 + 0], acc01);
                    acc01 = fma2(bc2(d1), w2p[k * 3 + 1], acc01);
                    acc01 = fma2(bc2(d2), w2p[k * 3 + 2], acc01);
                    acc0 = acc01.x; acc1 = acc01.y;
                    acc2 = fmaf(w2s[k * 3 + 0], d0, acc2);
                    acc2 = fmaf(w2s[k * 3 + 1], d1, acc2);
                    acc2 = fmaf(w2s[k * 3 + 2], d2, acc2);
                }
            }
        }
    } else {
        // ---- border blocks (20%): rolled exact loop ----
#pragma unroll 1
        for (int k = 0; k < 9; ++k) {
            const int kh = k / 3, kw = k - kh * 3;
            v2f pos; pos.x = (float)(ho + kh); pos.y = (float)(wo + kw);
            pos += off2[k];
            const v2f fl = __builtin_elementwise_floor(pos);
            const v2f fr = pos - fl;
            const int y0 = (int)fl.x;
            const int x0 = (int)fl.y;

            const int ry0 = min(max(y0, 0), HH - 1);
            const int ry1 = min(max(y0 + 1, 0), HH - 1);
            const int xbs = min(max(x0, 0), WW - 2);

            const bool vy0 = (y0 >= 0) & (y0 <= HH - 1);
            const bool vy1 = (y0 >= -1) & (y0 <= HH - 2);
            const bool vx0 = (x0 >= 0) & (x0 <= WW - 1);
            const bool vx1 = (x0 >= -1) & (x0 <= WW - 2);
            const float wy0m = vy0 ? (1.f - fr.x) : 0.f;
            const float wy1m = vy1 ? fr.x : 0.f;
            const float wx0m = vx0 ? (1.f - fr.y) : 0.f;
            const float wx1m = vx1 ? fr.y : 0.f;

            const bool selA = (x0 >= WW - 1);
            const bool selB = (x0 >= 0);
            const float e0 = (selA ? 0.f : wx0m) + (selB ? 0.f : wx1m);
            const float e1 = (selA ? wx0m : 0.f) + (selB ? wx1m : 0.f);
            const float g00 = wy0m * e0, g01 = wy0m * e1;
            const float g10 = wy1m * e0, g11 = wy1m * e1;

            const int ly0 = ry0 - gr0;
            const int ly1 = ry1 - gr0;
            const int lx  = xbs - gc0;
            const bool inTile = ((unsigned)ly0 <= SROWS - 1) &
                                ((unsigned)ly1 <= SROWS - 1) &
                                ((unsigned)lx  <= SCOLS - 2);

            const int cy0 = min(max(ly0, 0), SROWS - 1);
            const int cy1 = min(max(ly1, 0), SROWS - 1);
            const int cx  = min(max(lx, 0),  SCOLS - 2);
            const int ib0 = cy0 * SSTRIDE + cx;
            const int ib1 = cy1 * SSTRIDE + cx;
            v4f r0v = s_p01[ib0];
            v4f r1v = s_p01[ib1];
            v2f s0v = s_p2[ib0];
            v2f s1v = s_p2[ib1];

            if (!inTile) {
                const int o0 = ry0 * WW + xbs;
                const int o1 = ry1 * WW + xbs;
                r0v.x = xp0[o0];     r0v.y = xp1[o0];
                r0v.z = xp0[o0 + 1]; r0v.w = xp1[o0 + 1];
                s0v.x = xp2[o0];     s0v.y = xp2[o0 + 1];
                r1v.x = xp0[o1];     r1v.y = xp1[o1];
                r1v.z = xp0[o1 + 1]; r1v.w = xp1[o1 + 1];
                s1v.x = xp2[o1];     s1v.y = xp2[o1 + 1];
            }

            v2f t01 = bc2(g00) * lo2(r0v);
            t01 = fma2(bc2(g01), hi2(r0v), t01);
            t01 = fma2(bc2(g10), lo2(r1v), t01);
            t01 = fma2(bc2(g11), hi2(r1v), t01);
            float t2 = g00 * s0v.x;
            t2 = fmaf(g01, s0v.y, t2);
            t2 = fmaf(g10, s1v.x, t2);
            t2 = fmaf(g11, s1v.y, t2);

            const float v0 = t01.x, v1 = t01.y, v2v = t2;

            v2f acc01; acc01.x = acc0; acc01.y = acc1;
            acc01 = fma2(bc2(v0),  w2p[k * 3 + 0], acc01);
            acc01 = fma2(bc2(v1),  w2p[k * 3 + 1], acc01);
            acc01 = fma2(bc2(v2v), w2p[k * 3 + 2], acc01);
            acc0 = acc01.x; acc1 = acc01.y;
            acc2 = fmaf(w2s[k * 3 + 0], v0, acc2);
            acc2 = fmaf(w2s[k * 3 + 1], v1, acc2);
            acc2 = fmaf(w2s[k * 3 + 2], v2v, acc2);
        }
    }

    const long obase = ((long)(b * 3) * HO + ho) * WO + wo;
    __builtin_nontemporal_store(acc0, out + obase);
    __builtin_nontemporal_store(acc1, out + obase + (long)HO * WO);
    __builtin_nontemporal_store(acc2, out + obase + 2L * HO * WO);
}

extern "C" void kernel_launch(void* const* d_in, const int* in_sizes, int n_in,
                              void* d_out, int out_size, void* d_ws, size_t ws_size,
                              hipStream_t stream) {
    const float* x  = (const float*)d_in[0];
    const float* w1 = (const float*)d_in[1];
    const float* b1 = (const float*)d_in[2];
    const float* w2 = (const float*)d_in[3];
    const float* b2 = (const float*)d_in[4];
    float* out = (float*)d_out;
    float* ws  = (float*)d_ws;

    const int blocks = TILES_X * TILES_Y * BB;   // 12*48*8 = 4608
    const bool use_ws = (d_ws != nullptr) && (ws_size >= WS_FLOATS * sizeof(float));

    if (use_ws) {
        prep_weights<<<1, 512, 0, stream>>>(w1, w2, ws);
        deform_tiled<true><<<blocks, 256, 0, stream>>>(x, w1, b1, w2, b2, ws, out);
    } else {
        deform_tiled<false><<<blocks, 256, 0, stream>>>(x, w1, b1, w2, b2, nullptr, out);
    }
}